// Round 1
// baseline (1279.972 us; speedup 1.0000x reference)
//
#include <hip/hip_runtime.h>

// Problem constants (from reference setup_inputs)
#define NB 128        // batch
#define NK 100        // classes
#define NF 32768      // C*H*W = 128*16*16
#define NF4 (NF / 4)  // 8192 float4s per feature row
#define PROTO_ELEMS (NK * NF)  // 3,276,800 floats

// ws layout (int*): [0..NK) counts | [NK..2NK) offsets | [2NK..2NK+NB) sample list
__global__ void classify_kernel(const float* __restrict__ logits, int* __restrict__ ws) {
    __shared__ int s_cls[NB];
    __shared__ int s_counts[NK];
    __shared__ int s_off[NK];
    int t = threadIdx.x;
    if (t < NK) s_counts[t] = 0;
    __syncthreads();
    if (t < NB) {
        const float* row = logits + t * NK;
        float best = row[0];
        int bi = 0;
        for (int k = 1; k < NK; ++k) {
            float v = row[k];
            if (v > best) { best = v; bi = k; }  // first-max semantics, matches argmax
        }
        s_cls[t] = bi;
        atomicAdd(&s_counts[bi], 1);
    }
    __syncthreads();
    if (t == 0) {
        int run = 0;
        for (int k = 0; k < NK; ++k) { s_off[k] = run; run += s_counts[k]; }
    }
    __syncthreads();
    if (t < NK) {
        // deterministic, in-sample-order scatter (matches segment_sum accumulation order)
        int w = s_off[t];
        for (int b = 0; b < NB; ++b) {
            if (s_cls[b] == t) { ws[2 * NK + w] = b; ++w; }
        }
        ws[t] = s_counts[t];
        ws[NK + t] = s_off[t];
    }
}

// prototypes[k][f] = mean over samples assigned to class k (0 if empty class)
__global__ void proto_kernel(const float4* __restrict__ x4, const int* __restrict__ ws,
                             float4* __restrict__ out4) {
    int f = blockIdx.x * blockDim.x + threadIdx.x;  // 0..NF4
    int k = blockIdx.y;
    int cnt = ws[k];
    float4 acc = make_float4(0.f, 0.f, 0.f, 0.f);
    if (cnt > 0) {
        int off = ws[NK + k];
        for (int s = 0; s < cnt; ++s) {
            int b = ws[2 * NK + off + s];
            float4 v = x4[(long)b * NF4 + f];
            acc.x += v.x; acc.y += v.y; acc.z += v.z; acc.w += v.w;
        }
        float c = (float)cnt;
        acc.x /= c; acc.y /= c; acc.z /= c; acc.w /= c;
    }
    out4[(long)k * NF4 + f] = acc;
}

// inter[i][j][f] = proto[j][f] - proto[i][f]
__global__ void inter_kernel(const float4* __restrict__ proto4, float4* __restrict__ out4,
                             long total4) {
    long idx = (long)blockIdx.x * blockDim.x + threadIdx.x;
    if (idx >= total4) return;
    int f = (int)(idx & (NF4 - 1));   // NF4 = 8192 pow2
    int ij = (int)(idx >> 13);        // log2(NF4) = 13
    int i = ij / NK;                  // magic-mul div by 100
    int j = ij - i * NK;
    float4 a = proto4[(long)j * NF4 + f];
    float4 b = proto4[(long)i * NF4 + f];
    float4 r = make_float4(a.x - b.x, a.y - b.y, a.z - b.z, a.w - b.w);
    out4[idx] = r;
}

extern "C" void kernel_launch(void* const* d_in, const int* in_sizes, int n_in,
                              void* d_out, int out_size, void* d_ws, size_t ws_size,
                              hipStream_t stream) {
    const float* x = (const float*)d_in[0];
    const float* logits = (const float*)d_in[1];
    float* out = (float*)d_out;
    int* ws = (int*)d_ws;

    // 1) per-sample argmax + per-class lists (rebuilt every call; ws is re-poisoned)
    classify_kernel<<<1, 128, 0, stream>>>(logits, ws);

    // 2) prototypes -> d_out[0 .. PROTO_ELEMS)
    dim3 g2(NF4 / 256, NK);
    proto_kernel<<<g2, 256, 0, stream>>>((const float4*)x, ws, (float4*)out);

    // 3) inter-class matrix -> d_out[PROTO_ELEMS ..)
    long total4 = (long)NK * NK * NF4;  // 81,920,000 float4
    int blocks = (int)((total4 + 255) / 256);
    inter_kernel<<<blocks, 256, 0, stream>>>((const float4*)out,
                                             (float4*)(out + PROTO_ELEMS), total4);
}